// Round 1
// baseline (199.204 us; speedup 1.0000x reference)
//
#include <hip/hip_runtime.h>
#include <cstdint>
#include <cstddef>

// Genetic-code tables (compile-time so unrolled indexing constant-folds; rule #20)
static constexpr int kGOV[66] = {
  21,21, 9,12, 9,12,17,17,17,17,15,16,15,16, 8, 8,11, 8,14, 7,14, 7,
  13,13,13,13,15,15,15,15,10,10,10,10, 4, 3, 4, 3, 1, 1, 1, 1, 6, 6,
   6, 6,18,18,18,18, 0,20, 0,20,16,16,16,16, 0, 2,19, 2,10, 5,10, 5};
static constexpr float kNSYN[66] = {
  0,0, 2,2,2,2, 4,4,4,4, 6,6,6,6, 3,3,1,3, 2,2,2,2, 4,4,4,4,
  6,6,6,6, 6,6,6,6, 2,2,2,2, 4,4,4,4, 4,4,4,4, 4,4,4,4,
  3,2,3,2, 6,6,6,6, 3,2,1,2, 6,2,6,2};

__device__ __forceinline__ void gload_lds16(const void* g, void* l) {
  __builtin_amdgcn_global_load_lds(
      (const __attribute__((address_space(1))) void*)g,
      (__attribute__((address_space(3))) void*)l, 16, 0, 0);
}

// Kernel 1: per-position softmax stats + per-row/global partial reductions.
// Grid: B * (L/256) blocks, 256 threads. Each block: one 256-position chunk of one row.
__global__ __launch_bounds__(256, 2) void k_pos(
    const float* __restrict__ logits,
    const float* __restrict__ W,
    const int* __restrict__ tgt,
    const int* __restrict__ species,
    const unsigned char* __restrict__ mask,
    float* __restrict__ ws,
    int B, int L, int chunks_per_row)
{
  const int bid  = blockIdx.x;
  const int b    = bid / chunks_per_row;
  const int ch   = bid - b * chunks_per_row;
  const int l0   = ch * 256;
  const int tid  = threadIdx.x;
  const int lane = tid & 63;
  const int wave = tid >> 6;

  __shared__ float sL[256 * 66];     // 67584 B, linear copy of chunk
  __shared__ float s_logw[66];
  __shared__ int   s_cnt[132];       // [0..65]=pred counts, [66..131]=tgt counts
  __shared__ float s_acc[5];         // ce_num, ce_den, slogw_pred, slogw_tgt, mcount

  if (tid < 66) {
    int s = species[b];
    s_logw[tid] = __logf(fmaxf(W[s * 66 + tid], 1e-8f));
  }
  if (tid < 132) s_cnt[tid] = 0;
  if (tid < 5)  s_acc[tid] = 0.0f;

  // Stage 256 positions x 66 f32 = 4224 float4 (16B) into LDS, linear.
  const float* gbase = logits + ((size_t)b * L + l0) * 66;
  #pragma unroll
  for (int i = 0; i < 17; ++i) {
    int e = i * 256 + tid;                       // float4 index
    if (e < 4224) {                              // tail: waves 0,1 only (wave-uniform)
      gload_lds16(gbase + (size_t)e * 4,
                  (char*)sL + ((size_t)(i * 256 + wave * 64)) * 16);
    }
  }
  asm volatile("s_waitcnt vmcnt(0)" ::: "memory");
  __syncthreads();

  // Per-position compute (values held in registers, static indexing only)
  const float* xp = sL + tid * 66;
  float v[66];
  #pragma unroll
  for (int k = 0; k < 33; ++k) {
    float2 t = ((const float2*)xp)[k];
    v[2 * k] = t.x; v[2 * k + 1] = t.y;
  }
  float mx = v[0]; int pr = 0;
  #pragma unroll
  for (int k = 1; k < 66; ++k) { if (v[k] > mx) { mx = v[k]; pr = k; } }
  float se = 0.0f;
  #pragma unroll
  for (int k = 0; k < 66; ++k) se += __expf(v[k] - mx);

  const int pos = b * L + l0 + tid;
  const int tg  = tgt[pos];
  const float xt   = xp[tg];                 // LDS read (runtime index), not v[]
  const float mval = mask[pos] ? 1.0f : 0.0f;
  const float nll  = __logf(se) + mx - xt;
  const float ce_n = (tg != 0) ? nll : 0.0f;
  const float ce_d = (tg != 0) ? 1.0f : 0.0f;
  const float lw_p = s_logw[pr] * mval;
  const float lw_t = s_logw[tg] * mval;

  if (mval != 0.0f) {
    if (pr >= 2) atomicAdd(&s_cnt[pr], 1);
    if (tg >= 2) atomicAdd(&s_cnt[66 + tg], 1);
  }

  float r0 = ce_n, r1 = ce_d, r2 = lw_p, r3 = lw_t, r4 = mval;
  #pragma unroll
  for (int off = 32; off > 0; off >>= 1) {
    r0 += __shfl_xor(r0, off);
    r1 += __shfl_xor(r1, off);
    r2 += __shfl_xor(r2, off);
    r3 += __shfl_xor(r3, off);
    r4 += __shfl_xor(r4, off);
  }
  if (lane == 0) {
    atomicAdd(&s_acc[0], r0);
    atomicAdd(&s_acc[1], r1);
    atomicAdd(&s_acc[2], r2);
    atomicAdd(&s_acc[3], r3);
    atomicAdd(&s_acc[4], r4);
  }
  __syncthreads();

  int* wsi = (int*)ws;
  const int off_slp = 2, off_slt = 2 + B, off_mc = 2 + 2 * B, off_cp = 2 + 3 * B;
  const int off_ct = off_cp + B * 66;
  if (tid == 0) {
    atomicAdd(&ws[0], s_acc[0]);
    atomicAdd(&ws[1], s_acc[1]);
    atomicAdd(&ws[off_slp + b], s_acc[2]);
    atomicAdd(&ws[off_slt + b], s_acc[3]);
    atomicAdd(&ws[off_mc + b], s_acc[4]);
  }
  if (tid < 66)       atomicAdd(&wsi[off_cp + b * 66 + tid], s_cnt[tid]);
  else if (tid < 132) atomicAdd(&wsi[off_ct + b * 66 + (tid - 66)], s_cnt[tid]);
}

// Kernel 2: per-row CAI + RSCU-KL, then final scalar. 1 block, B threads.
__global__ void k_final(
    const float* __restrict__ refd,
    const int* __restrict__ species,
    const float* __restrict__ ws,
    float* __restrict__ out, int B)
{
  const int b = threadIdx.x;
  const int lane = b & 63, wave = b >> 6;
  const int off_slp = 2, off_slt = 2 + B, off_mc = 2 + 2 * B, off_cp = 2 + 3 * B;
  const int off_ct = off_cp + B * 66;
  const int* wsi = (const int*)ws;

  float cai_l = 0.0f, kl = 0.0f;
  if (b < B) {
    float mc = fmaxf(ws[off_mc + b], 1.0f);
    float cai_p = __expf(ws[off_slp + b] / mc);
    float cai_t = __expf(ws[off_slt + b] / mc);
    cai_l = fmaxf(cai_t - cai_p, 0.0f);

    const int* cp = wsi + off_cp + b * 66;
    const int* ct = wsi + off_ct + b * 66;
    float gtp[22], gtt[22];
    #pragma unroll
    for (int g = 0; g < 22; ++g) { gtp[g] = 0.0f; gtt[g] = 0.0f; }
    #pragma unroll
    for (int v = 0; v < 66; ++v) {
      gtp[kGOV[v]] += (float)cp[v];
      gtt[kGOV[v]] += (float)ct[v];
    }
    const int s = species[b];
    float psum = 0.0f, tsum = 0.0f;
    #pragma unroll
    for (int v = 0; v < 66; ++v) {
      float gp = gtp[kGOV[v]];
      float rp = gp > 0.0f ? (float)cp[v] * kNSYN[v] / gp : 0.0f;
      psum += rp + 1e-8f;
      float gt = gtt[kGOV[v]];
      float rt = gt > 0.0f ? (float)ct[v] * kNSYN[v] / gt : 0.0f;
      tsum += 0.7f * rt + 0.3f * refd[s * 66 + v] + 1e-8f;
    }
    #pragma unroll
    for (int v = 0; v < 66; ++v) {
      float gp = gtp[kGOV[v]];
      float rp = gp > 0.0f ? (float)cp[v] * kNSYN[v] / gp : 0.0f;
      float pv = (rp + 1e-8f) / psum;
      float gt = gtt[kGOV[v]];
      float rt = gt > 0.0f ? (float)ct[v] * kNSYN[v] / gt : 0.0f;
      float tv = (0.7f * rt + 0.3f * refd[s * 66 + v] + 1e-8f) / tsum;
      kl += tv * __logf(tv / pv);
    }
  }
  #pragma unroll
  for (int off = 32; off > 0; off >>= 1) {
    cai_l += __shfl_xor(cai_l, off);
    kl    += __shfl_xor(kl, off);
  }
  __shared__ float sc[16], sk[16];
  if (lane == 0) { sc[wave] = cai_l; sk[wave] = kl; }
  __syncthreads();
  if (b == 0) {
    int nw = (blockDim.x + 63) >> 6;
    float c = 0.0f, k2 = 0.0f;
    for (int w2 = 0; w2 < nw; ++w2) { c += sc[w2]; k2 += sk[w2]; }
    float ce = ws[0] / fmaxf(ws[1], 1.0f);
    out[0] = ce + 0.4f * (c / (float)B) + 0.3f * (k2 / (float)B);
  }
}

extern "C" void kernel_launch(void* const* d_in, const int* in_sizes, int n_in,
                              void* d_out, int out_size, void* d_ws, size_t ws_size,
                              hipStream_t stream) {
  const float* logits  = (const float*)d_in[0];
  const float* W       = (const float*)d_in[1];
  const float* refd    = (const float*)d_in[2];
  const int*   tgt     = (const int*)d_in[3];
  // d_in[4] = aa_ids: unused by the reference
  const int*   species = (const int*)d_in[5];
  const unsigned char* mask = (const unsigned char*)d_in[6];  // numpy bool = 1 byte
  float* out = (float*)d_out;
  float* ws  = (float*)d_ws;

  const int B = in_sizes[5];
  const int L = in_sizes[3] / B;       // 4096
  const int cpr = L / 256;             // chunks per row

  const int ws_words = 2 + 3 * B + 2 * B * 66;
  hipMemsetAsync(d_ws, 0, (size_t)ws_words * 4, stream);

  hipLaunchKernelGGL(k_pos, dim3(B * cpr), dim3(256), 0, stream,
                     logits, W, tgt, species, mask, ws, B, L, cpr);
  hipLaunchKernelGGL(k_final, dim3(1), dim3(B), 0, stream,
                     refd, species, ws, out, B);
}

// Round 2
// 83.822 us; speedup vs baseline: 2.3765x; 2.3765x over previous
//
#include <hip/hip_runtime.h>
#include <cstdint>
#include <cstddef>

// Genetic-code tables. Host-constexpr copies for any compile-time use,
// device arrays for runtime-indexed access (no per-thread arrays -> no scratch).
__device__ static const int   d_GOV[66] = {
  21,21, 9,12, 9,12,17,17,17,17,15,16,15,16, 8, 8,11, 8,14, 7,14, 7,
  13,13,13,13,15,15,15,15,10,10,10,10, 4, 3, 4, 3, 1, 1, 1, 1, 6, 6,
   6, 6,18,18,18,18, 0,20, 0,20,16,16,16,16, 0, 2,19, 2,10, 5,10, 5};
__device__ static const float d_NSYN[66] = {
  0,0, 2,2,2,2, 4,4,4,4, 6,6,6,6, 3,3,1,3, 2,2,2,2, 4,4,4,4,
  6,6,6,6, 6,6,6,6, 2,2,2,2, 4,4,4,4, 4,4,4,4, 4,4,4,4,
  3,2,3,2, 6,6,6,6, 3,2,1,2, 6,2,6,2};

__device__ __forceinline__ void gload_lds16(const void* g, void* l) {
  __builtin_amdgcn_global_load_lds(
      (const __attribute__((address_space(1))) void*)g,
      (__attribute__((address_space(3))) void*)l, 16, 0, 0);
}

// Kernel 1: per-position softmax stats + per-row/global partial reductions.
// Grid: B * (L/256) blocks, 256 threads. Each block: one 256-position chunk of one row.
__global__ __launch_bounds__(256, 2) void k_pos(
    const float* __restrict__ logits,
    const float* __restrict__ W,
    const int* __restrict__ tgt,
    const int* __restrict__ species,
    const unsigned char* __restrict__ mask,
    float* __restrict__ ws,
    int B, int L, int chunks_per_row)
{
  const int bid  = blockIdx.x;
  const int b    = bid / chunks_per_row;
  const int ch   = bid - b * chunks_per_row;
  const int l0   = ch * 256;
  const int tid  = threadIdx.x;
  const int lane = tid & 63;
  const int wave = tid >> 6;

  __shared__ float sL[256 * 66];     // 67584 B, linear copy of chunk
  __shared__ float s_logw[66];
  __shared__ int   s_cnt[132];       // [0..65]=pred counts, [66..131]=tgt counts
  __shared__ float s_acc[5];         // ce_num, ce_den, slogw_pred, slogw_tgt, mcount

  if (tid < 66) {
    int s = species[b];
    s_logw[tid] = __logf(fmaxf(W[s * 66 + tid], 1e-8f));
  }
  if (tid < 132) s_cnt[tid] = 0;
  if (tid < 5)  s_acc[tid] = 0.0f;

  // Stage 256 positions x 66 f32 = 4224 float4 (16B) into LDS, linear.
  const float* gbase = logits + ((size_t)b * L + l0) * 66;
  #pragma unroll
  for (int i = 0; i < 17; ++i) {
    int e = i * 256 + tid;                       // float4 index
    if (e < 4224) {                              // tail: waves 0,1 only (wave-uniform)
      gload_lds16(gbase + (size_t)e * 4,
                  (char*)sL + ((size_t)(i * 256 + wave * 64)) * 16);
    }
  }
  asm volatile("s_waitcnt vmcnt(0)" ::: "memory");
  __syncthreads();

  // Per-position compute (values held in registers, static indexing only)
  const float* xp = sL + tid * 66;
  float v[66];
  #pragma unroll
  for (int k = 0; k < 33; ++k) {
    float2 t = ((const float2*)xp)[k];
    v[2 * k] = t.x; v[2 * k + 1] = t.y;
  }
  float mx = v[0]; int pr = 0;
  #pragma unroll
  for (int k = 1; k < 66; ++k) { if (v[k] > mx) { mx = v[k]; pr = k; } }
  float se = 0.0f;
  #pragma unroll
  for (int k = 0; k < 66; ++k) se += __expf(v[k] - mx);

  const int pos = b * L + l0 + tid;
  const int tg  = tgt[pos];
  const float xt   = xp[tg];                 // LDS read (runtime index), not v[]
  const float mval = mask[pos] ? 1.0f : 0.0f;
  const float nll  = __logf(se) + mx - xt;
  const float ce_n = (tg != 0) ? nll : 0.0f;
  const float ce_d = (tg != 0) ? 1.0f : 0.0f;
  const float lw_p = s_logw[pr] * mval;
  const float lw_t = s_logw[tg] * mval;

  if (mval != 0.0f) {
    if (pr >= 2) atomicAdd(&s_cnt[pr], 1);
    if (tg >= 2) atomicAdd(&s_cnt[66 + tg], 1);
  }

  float r0 = ce_n, r1 = ce_d, r2 = lw_p, r3 = lw_t, r4 = mval;
  #pragma unroll
  for (int off = 32; off > 0; off >>= 1) {
    r0 += __shfl_xor(r0, off);
    r1 += __shfl_xor(r1, off);
    r2 += __shfl_xor(r2, off);
    r3 += __shfl_xor(r3, off);
    r4 += __shfl_xor(r4, off);
  }
  if (lane == 0) {
    atomicAdd(&s_acc[0], r0);
    atomicAdd(&s_acc[1], r1);
    atomicAdd(&s_acc[2], r2);
    atomicAdd(&s_acc[3], r3);
    atomicAdd(&s_acc[4], r4);
  }
  __syncthreads();

  int* wsi = (int*)ws;
  const int off_slp = 2, off_slt = 2 + B, off_mc = 2 + 2 * B, off_cp = 2 + 3 * B;
  const int off_ct = off_cp + B * 66;
  if (tid == 0) {
    atomicAdd(&ws[0], s_acc[0]);
    atomicAdd(&ws[1], s_acc[1]);
    atomicAdd(&ws[off_slp + b], s_acc[2]);
    atomicAdd(&ws[off_slt + b], s_acc[3]);
    atomicAdd(&ws[off_mc + b], s_acc[4]);
  }
  if (tid < 66)       atomicAdd(&wsi[off_cp + b * 66 + tid], s_cnt[tid]);
  else if (tid < 132) atomicAdd(&wsi[off_ct + b * 66 + (tid - 66)], s_cnt[tid]);
}

// Kernel 2: per-row CAI + RSCU-KL, codon-parallel. Grid: B blocks x 128 threads.
// Thread v in [0,66) owns codon v. No per-thread arrays -> no scratch.
__global__ __launch_bounds__(128) void k_row(
    const float* __restrict__ refd,
    const int* __restrict__ species,
    float* __restrict__ ws,
    int B)
{
  const int b    = blockIdx.x;
  const int tid  = threadIdx.x;
  const int lane = tid & 63;
  const int wave = tid >> 6;
  const int off_slp = 2, off_slt = 2 + B, off_mc = 2 + 2 * B, off_cp = 2 + 3 * B;
  const int off_ct = off_cp + B * 66;
  const int off_res = off_ct + B * 66;
  const int* wsi = (const int*)ws;

  __shared__ float gp[24], gt[24];
  __shared__ float red[8];
  if (tid < 24) { gp[tid] = 0.0f; gt[tid] = 0.0f; }
  __syncthreads();

  float cp = 0.0f, ct = 0.0f, nsyn = 0.0f, ref = 0.0f;
  int gov = 22;
  if (tid < 66) {
    cp = (float)wsi[off_cp + b * 66 + tid];
    ct = (float)wsi[off_ct + b * 66 + tid];
    gov  = d_GOV[tid];
    nsyn = d_NSYN[tid];
    ref  = refd[species[b] * 66 + tid];
    atomicAdd(&gp[gov], cp);   // integer-valued floats: order-independent exact
    atomicAdd(&gt[gov], ct);
  }
  __syncthreads();

  float rp = 0.0f, rt = 0.0f;
  if (tid < 66) {
    float g1 = gp[gov]; rp = (g1 > 0.0f) ? cp * nsyn / g1 : 0.0f;
    float g2 = gt[gov]; rt = (g2 > 0.0f) ? ct * nsyn / g2 : 0.0f;
  }
  float pp = (tid < 66) ? (rp + 1e-8f) : 0.0f;
  float tp = (tid < 66) ? (0.7f * rt + 0.3f * ref + 1e-8f) : 0.0f;
  #pragma unroll
  for (int off = 32; off > 0; off >>= 1) {
    pp += __shfl_xor(pp, off);
    tp += __shfl_xor(tp, off);
  }
  if (lane == 0) { red[wave * 2] = pp; red[wave * 2 + 1] = tp; }
  __syncthreads();
  const float psum = red[0] + red[2];
  const float tsum = red[1] + red[3];

  float kl = 0.0f;
  if (tid < 66) {
    float pv = (rp + 1e-8f) / psum;
    float tv = (0.7f * rt + 0.3f * ref + 1e-8f) / tsum;
    kl = tv * __logf(tv / pv);
  }
  #pragma unroll
  for (int off = 32; off > 0; off >>= 1) kl += __shfl_xor(kl, off);
  if (lane == 0) red[4 + wave] = kl;
  __syncthreads();

  if (tid == 0) {
    float klt = red[4] + red[5];
    float mc    = fmaxf(ws[off_mc + b], 1.0f);
    float cai_p = __expf(ws[off_slp + b] / mc);
    float cai_t = __expf(ws[off_slt + b] / mc);
    float cai_l = fmaxf(cai_t - cai_p, 0.0f);
    ws[off_res + b] = 0.4f * cai_l + 0.3f * klt;
  }
}

// Kernel 3: final scalar. 1 block, B threads.
__global__ __launch_bounds__(128) void k_sum(
    const float* __restrict__ ws,
    float* __restrict__ out, int B)
{
  const int b = threadIdx.x;
  const int lane = b & 63, wave = b >> 6;
  const int off_res = 2 + 3 * B + 2 * B * 66;
  float r = (b < B) ? ws[off_res + b] : 0.0f;
  #pragma unroll
  for (int off = 32; off > 0; off >>= 1) r += __shfl_xor(r, off);
  __shared__ float sr[2];
  if (lane == 0) sr[wave] = r;
  __syncthreads();
  if (b == 0) {
    float ce = ws[0] / fmaxf(ws[1], 1.0f);
    out[0] = ce + (sr[0] + sr[1]) / (float)B;
  }
}

extern "C" void kernel_launch(void* const* d_in, const int* in_sizes, int n_in,
                              void* d_out, int out_size, void* d_ws, size_t ws_size,
                              hipStream_t stream) {
  const float* logits  = (const float*)d_in[0];
  const float* W       = (const float*)d_in[1];
  const float* refd    = (const float*)d_in[2];
  const int*   tgt     = (const int*)d_in[3];
  // d_in[4] = aa_ids: unused by the reference
  const int*   species = (const int*)d_in[5];
  const unsigned char* mask = (const unsigned char*)d_in[6];  // numpy bool = 1 byte
  float* out = (float*)d_out;
  float* ws  = (float*)d_ws;

  const int B = in_sizes[5];
  const int L = in_sizes[3] / B;       // 4096
  const int cpr = L / 256;             // chunks per row

  const int ws_words = 2 + 3 * B + 2 * B * 66 + B;
  hipMemsetAsync(d_ws, 0, (size_t)ws_words * 4, stream);

  hipLaunchKernelGGL(k_pos, dim3(B * cpr), dim3(256), 0, stream,
                     logits, W, tgt, species, mask, ws, B, L, cpr);
  hipLaunchKernelGGL(k_row, dim3(B), dim3(128), 0, stream,
                     refd, species, ws, B);
  hipLaunchKernelGGL(k_sum, dim3(1), dim3(128), 0, stream,
                     ws, out, B);
}